// Round 1
// baseline (321.236 us; speedup 1.0000x reference)
//
#include <hip/hip_runtime.h>

// Fields: 16 independent tiny MLPs (3 -> 16 -> 16 -> 3, relu, relu, linear)
// applied pointwise to 1M points. fp32 throughout.
//
// Strategy (R1): pure fp32 VALU kernel. One thread = 2 points packed in
// float2 ext-vectors so the AMDGPU backend can emit v_pk_fma_f32 (dual fp32
// FMA). Weights are wave-uniform -> expect s_load on the scalar pipe.
// d-loop rolled (16 iters, ~3KB code each) to stay inside I$.

typedef float v2f __attribute__((ext_vector_type(2)));

#define D_FIELDS 16
#define HIDDEN 16

__global__ __launch_bounds__(256) void fields_mlp_kernel(
    const float* __restrict__ x,
    const float* __restrict__ W1, const float* __restrict__ b1,
    const float* __restrict__ W2, const float* __restrict__ b2,
    const float* __restrict__ W3, const float* __restrict__ b3,
    float* __restrict__ out, int N)
{
    const int pair = blockIdx.x * blockDim.x + threadIdx.x;
    const int n0 = pair * 2;
    if (n0 >= N) return;

    // x layout: [3, N] -> three coalesced float2 streams
    v2f xv[3];
#pragma unroll
    for (int c = 0; c < 3; ++c)
        xv[c] = *(const v2f*)(x + (size_t)c * N + n0);

    for (int d = 0; d < D_FIELDS; ++d) {
        const float* w1  = W1 + d * HIDDEN * 3;     // [16,3]
        const float* bb1 = b1 + d * HIDDEN;         // [16]
        const float* w2  = W2 + d * HIDDEN * HIDDEN;// [16,16]
        const float* bb2 = b2 + d * HIDDEN;         // [16]
        const float* w3  = W3 + d * 3 * HIDDEN;     // [3,16]
        const float* bb3 = b3 + d * 3;              // [3]

        // Layer 1: h1 = relu(W1 @ x + b1)
        v2f h1[HIDDEN];
#pragma unroll
        for (int h = 0; h < HIDDEN; ++h) {
            v2f acc = bb1[h];            // scalar splat
#pragma unroll
            for (int c = 0; c < 3; ++c)
                acc += w1[h * 3 + c] * xv[c];
            h1[h].x = fmaxf(acc.x, 0.0f);
            h1[h].y = fmaxf(acc.y, 0.0f);
        }

        // Layer 2: h2 = relu(W2 @ h1 + b2)
        v2f h2[HIDDEN];
#pragma unroll
        for (int g = 0; g < HIDDEN; ++g) {
            v2f acc = bb2[g];
#pragma unroll
            for (int h = 0; h < HIDDEN; ++h)
                acc += w2[g * HIDDEN + h] * h1[h];
            h2[g].x = fmaxf(acc.x, 0.0f);
            h2[g].y = fmaxf(acc.y, 0.0f);
        }

        // Layer 3: out[d] = W3 @ h2 + b3   (no relu)
#pragma unroll
        for (int o = 0; o < 3; ++o) {
            v2f acc = bb3[o];
#pragma unroll
            for (int h = 0; h < HIDDEN; ++h)
                acc += w3[o * HIDDEN + h] * h2[h];
            *(v2f*)(out + (size_t)d * 3 * N + (size_t)o * N + n0) = acc;
        }
    }
}

extern "C" void kernel_launch(void* const* d_in, const int* in_sizes, int n_in,
                              void* d_out, int out_size, void* d_ws, size_t ws_size,
                              hipStream_t stream) {
    const float* x  = (const float*)d_in[0];
    const float* W1 = (const float*)d_in[1];
    const float* b1 = (const float*)d_in[2];
    const float* W2 = (const float*)d_in[3];
    const float* b2 = (const float*)d_in[4];
    const float* W3 = (const float*)d_in[5];
    const float* b3 = (const float*)d_in[6];
    float* out = (float*)d_out;

    const int N = in_sizes[0] / 3;   // x is [1,3,N]
    const int pairs = N / 2;         // N = 1e6, even
    const int block = 256;
    const int grid = (pairs + block - 1) / block;
    fields_mlp_kernel<<<grid, block, 0, stream>>>(x, W1, b1, W2, b2, W3, b3, out, N);
}

// Round 3
// 282.102 us; speedup vs baseline: 1.1387x; 1.1387x over previous
//
#include <hip/hip_runtime.h>

// Fields: 16 MLPs (3->16->16->3) over 1M points. R3: f16 MFMA path
// (R2 with the cvt_pkrtz return-type fix: builtin returns __fp16 x2).
//
// Orientation: channels = M (A = weights), points = N (B = activations).
// mfma_f32_16x16x32_f16: D[16,16] = A[16x32] B[32x16], fp32 accum.
//   A-frag: lane m=lane&15 holds k = 8*(lane>>4)+j, j=0..7
//   B-frag: lane n=lane&15 holds k = 8*(lane>>4)+j
//   C/D:    lane holds col n=lane&15, rows r = 4*(lane>>4)+i, i=0..3
// K padding: K=3 (L1) / K=16 (L2,L3) -> quads beyond valid k carry zeros.
// Transition D->B (16 valid k): dest lane (n,q) needs rows 8q..8q+7 =
// packed regs of source lanes n+32q (rows 8q..8q+3) and n+32q+16 (8q+4..8q+7)
// -> 4 ds_bpermute per transition, register-only, no barrier.
// Bias rides in the MFMA C operand (fp32, exact). Weights pre-staged once
// per block into frag-ready LDS (~29 KB).

#define TILES_PER_WAVE 5
#define WAVES_PER_BLOCK 4
#define PTS_PER_BLOCK (TILES_PER_WAVE * WAVES_PER_BLOCK * 16)  // 320; 1e6 = 3125*320

typedef __fp16 pk16x2 __attribute__((ext_vector_type(2)));   // cvt_pkrtz return type
typedef _Float16 half8_t __attribute__((ext_vector_type(8)));
typedef float float4_t __attribute__((ext_vector_type(4)));

union H2I { pk16x2 h; int i; };
union Frag { half8_t v; int i[4]; };

__device__ __forceinline__ int pkrtz(float a, float b) {
    H2I u; u.h = __builtin_amdgcn_cvt_pkrtz(a, b); return u.i;
}

__global__ __launch_bounds__(256) void fields_mfma_kernel(
    const float* __restrict__ x,
    const float* __restrict__ W1, const float* __restrict__ b1,
    const float* __restrict__ W2, const float* __restrict__ b2,
    const float* __restrict__ W3, const float* __restrict__ b3,
    float* __restrict__ out, int N)
{
    // ---- frag-ready weight staging in LDS (once per block) ----
    __shared__ __align__(16) _Float16 A1c[16][16][4];   // [d][m][{w0,w1,w2,0}]   2 KB
    __shared__ __align__(16) _Float16 A2c[16][16][24];  // 48B stride, 16 used   12 KB
    __shared__ __align__(16) _Float16 A3c[16][16][24];  //                        12 KB
    __shared__ __align__(16) float B1c[16][16];         // bias rows              1 KB
    __shared__ __align__(16) float B2c[16][16];
    __shared__ __align__(16) float B3c[16][16];         // padded to 16, o>=3 -> 0

    {
        const int td = threadIdx.x;        // 256 threads = (d,m) pairs
        const int d = td >> 4, m = td & 15;
        const float* w1 = W1 + (d * 16 + m) * 3;
        A1c[d][m][0] = (_Float16)w1[0];
        A1c[d][m][1] = (_Float16)w1[1];
        A1c[d][m][2] = (_Float16)w1[2];
        A1c[d][m][3] = (_Float16)0.f;
        const float* w2 = W2 + (d * 16 + m) * 16;
#pragma unroll
        for (int k = 0; k < 16; ++k) A2c[d][m][k] = (_Float16)w2[k];
        if (m < 3) {
            const float* w3 = W3 + (d * 3 + m) * 16;
#pragma unroll
            for (int k = 0; k < 16; ++k) A3c[d][m][k] = (_Float16)w3[k];
        } else {
#pragma unroll
            for (int k = 0; k < 16; ++k) A3c[d][m][k] = (_Float16)0.f;
        }
        B1c[d][m] = b1[d * 16 + m];
        B2c[d][m] = b2[d * 16 + m];
        B3c[d][m] = (m < 3) ? b3[d * 3 + m] : 0.f;
    }
    __syncthreads();

    const int lane = threadIdx.x & 63;
    const int wave = threadIdx.x >> 6;
    const int q = lane >> 4;        // quad 0..3
    const int n16 = lane & 15;      // column within tile

    // bpermute byte selectors: sources n+32q and n+32q+16 (wrapped; q>=2 zeroed)
    const int selA = (((n16 + 32 * q) & 63) << 2);
    const int selB = (((n16 + 32 * q + 16) & 63) << 2);

    const int base = blockIdx.x * PTS_PER_BLOCK + wave * (TILES_PER_WAVE * 16);

    // ---- x B-frags (K=3: quad 0 regs {pk(x0,x1), pk(x2,0)}, rest zero) ----
    Frag xf[TILES_PER_WAVE];
#pragma unroll
    for (int t = 0; t < TILES_PER_WAVE; ++t) {
        const int pt = base + t * 16 + n16;
        float x0 = 0.f, x1 = 0.f, x2 = 0.f;
        if (q == 0 && pt < N) {
            x0 = x[pt];
            x1 = x[(size_t)N + pt];
            x2 = x[2 * (size_t)N + pt];
        }
        xf[t].i[0] = pkrtz(x0, x1);
        xf[t].i[1] = pkrtz(x2, 0.f);
        xf[t].i[2] = 0;
        xf[t].i[3] = 0;
    }

#pragma unroll 1
    for (int d = 0; d < 16; ++d) {
        // A-frags from LDS (lane m = n16)
        Frag a1;
        {
            const int* p = (const int*)&A1c[d][n16][0];
            a1.i[0] = (q == 0) ? p[0] : 0;
            a1.i[1] = (q == 0) ? p[1] : 0;
            a1.i[2] = 0; a1.i[3] = 0;
        }
        Frag a2, a3;
        {
            a2.v = *(const half8_t*)&A2c[d][n16][(q & 1) * 8];
            a3.v = *(const half8_t*)&A3c[d][n16][(q & 1) * 8];
            if (q >= 2) { a2.i[0]=0; a2.i[1]=0; a2.i[2]=0; a2.i[3]=0;
                          a3.i[0]=0; a3.i[1]=0; a3.i[2]=0; a3.i[3]=0; }
        }
        const float4_t bias1 = *(const float4_t*)&B1c[d][q * 4];
        const float4_t bias2 = *(const float4_t*)&B2c[d][q * 4];
        const float4_t bias3 = *(const float4_t*)&B3c[d][q * 4];

#pragma unroll
        for (int t = 0; t < TILES_PER_WAVE; ++t) {
            // Layer 1
            float4_t acc = bias1;
            acc = __builtin_amdgcn_mfma_f32_16x16x32_f16(a1.v, xf[t].v, acc, 0, 0, 0);
            // relu + D->B transition
            int p0 = pkrtz(fmaxf(acc.x, 0.f), fmaxf(acc.y, 0.f));
            int p1 = pkrtz(fmaxf(acc.z, 0.f), fmaxf(acc.w, 0.f));
            Frag bf;
            bf.i[0] = __builtin_amdgcn_ds_bpermute(selA, p0);
            bf.i[1] = __builtin_amdgcn_ds_bpermute(selA, p1);
            bf.i[2] = __builtin_amdgcn_ds_bpermute(selB, p0);
            bf.i[3] = __builtin_amdgcn_ds_bpermute(selB, p1);
            if (q >= 2) { bf.i[0]=0; bf.i[1]=0; bf.i[2]=0; bf.i[3]=0; }
            // Layer 2
            acc = bias2;
            acc = __builtin_amdgcn_mfma_f32_16x16x32_f16(a2.v, bf.v, acc, 0, 0, 0);
            p0 = pkrtz(fmaxf(acc.x, 0.f), fmaxf(acc.y, 0.f));
            p1 = pkrtz(fmaxf(acc.z, 0.f), fmaxf(acc.w, 0.f));
            Frag cf;
            cf.i[0] = __builtin_amdgcn_ds_bpermute(selA, p0);
            cf.i[1] = __builtin_amdgcn_ds_bpermute(selA, p1);
            cf.i[2] = __builtin_amdgcn_ds_bpermute(selB, p0);
            cf.i[3] = __builtin_amdgcn_ds_bpermute(selB, p1);
            if (q >= 2) { cf.i[0]=0; cf.i[1]=0; cf.i[2]=0; cf.i[3]=0; }
            // Layer 3 (no relu)
            acc = bias3;
            acc = __builtin_amdgcn_mfma_f32_16x16x32_f16(a3.v, cf.v, acc, 0, 0, 0);
            // store: quad 0 holds rows 0..3 -> outputs o=0,1,2 of column n
            const int pt = base + t * 16 + n16;
            if (q == 0 && pt < N) {
                out[(size_t)(d * 3 + 0) * N + pt] = acc.x;
                out[(size_t)(d * 3 + 1) * N + pt] = acc.y;
                out[(size_t)(d * 3 + 2) * N + pt] = acc.z;
            }
        }
    }
}

extern "C" void kernel_launch(void* const* d_in, const int* in_sizes, int n_in,
                              void* d_out, int out_size, void* d_ws, size_t ws_size,
                              hipStream_t stream) {
    const float* x  = (const float*)d_in[0];
    const float* W1 = (const float*)d_in[1];
    const float* b1 = (const float*)d_in[2];
    const float* W2 = (const float*)d_in[3];
    const float* b2 = (const float*)d_in[4];
    const float* W3 = (const float*)d_in[5];
    const float* b3 = (const float*)d_in[6];
    float* out = (float*)d_out;

    const int N = in_sizes[0] / 3;  // x is [1,3,N]
    const int grid = (N + PTS_PER_BLOCK - 1) / PTS_PER_BLOCK;
    fields_mfma_kernel<<<grid, 256, 0, stream>>>(x, W1, b1, W2, b2, W3, b3, out, N);
}

// Round 5
// 250.805 us; speedup vs baseline: 1.2808x; 1.1248x over previous
//
#include <hip/hip_runtime.h>

// Fields: 16 MLPs (3->16->16->3) over 1M points. R5: chain layers with the
// LEGACY mfma_f32_16x16x16f16 shape (legacy spelling, no underscore — the
// __has_builtin guard failed on the HOST pass in R4), whose B-frag
// (k = 4*quad + j) matches the C/D-frag (row = 4*quad + i) quad-for-quad,
// reg-for-reg. The D->B transition between layers is pure per-lane register
// work: 4 fmax + 2 cvt_pkrtz. No ds_bpermute, no K zero-masking (K=16 exact
// for L2/L3; L1's K=3 pads inside quad 0 and B's quads>=1 are true zeros,
// so A's quads>=1 may hold anything finite).
//
// Frag layouts (16x16x16, CDNA family):
//   A[m][k]: lane m=lane&15, k = 4*(lane>>4) + j   (4 f16, 2 VGPRs)
//   B[k][n]: lane n=lane&15, k = 4*(lane>>4) + j
//   C/D:     lane n=lane&15, row = 4*(lane>>4) + i (4 fp32)
// Bias rides in the MFMA C operand (fp32, exact).

#define MFMA16(a, b, c) __builtin_amdgcn_mfma_f32_16x16x16f16((a), (b), (c), 0, 0, 0)

#define TILES_PER_WAVE 5
#define WAVES_PER_BLOCK 4
#define PTS_PER_BLOCK (TILES_PER_WAVE * WAVES_PER_BLOCK * 16)  // 320; 1e6 = 3125*320

typedef __fp16 pk16x2 __attribute__((ext_vector_type(2)));   // cvt_pkrtz return type
typedef _Float16 half4_t __attribute__((ext_vector_type(4)));
typedef float float4_t __attribute__((ext_vector_type(4)));

union H2I { pk16x2 h; int i; };
union Frag { half4_t v; int i[2]; };

__device__ __forceinline__ int pkrtz(float a, float b) {
    H2I u; u.h = __builtin_amdgcn_cvt_pkrtz(a, b); return u.i;
}

__global__ __launch_bounds__(256) void fields_mfma16_kernel(
    const float* __restrict__ x,
    const float* __restrict__ W1, const float* __restrict__ b1,
    const float* __restrict__ W2, const float* __restrict__ b2,
    const float* __restrict__ W3, const float* __restrict__ b3,
    float* __restrict__ out, int N)
{
    // ---- frag-ready weight staging in LDS (once per block, ~21.5 KB) ----
    __shared__ __align__(16) _Float16 A1c[16][16][4];   // [d][m][{w0,w1,w2,0}]
    __shared__ __align__(16) _Float16 A2c[16][16][16];  // [d][m=g][k=h]
    __shared__ __align__(16) _Float16 A3c[16][16][16];  // [d][m=o][k=h], m>=3 -> 0
    __shared__ __align__(16) float B1c[16][16];
    __shared__ __align__(16) float B2c[16][16];
    __shared__ __align__(16) float B3c[16][16];         // rows 3..15 -> 0

    {
        const int td = threadIdx.x;        // 256 threads = (d,m) pairs
        const int d = td >> 4, m = td & 15;
        const float* w1 = W1 + (d * 16 + m) * 3;
        A1c[d][m][0] = (_Float16)w1[0];
        A1c[d][m][1] = (_Float16)w1[1];
        A1c[d][m][2] = (_Float16)w1[2];
        A1c[d][m][3] = (_Float16)0.f;
        const float* w2 = W2 + (d * 16 + m) * 16;
#pragma unroll
        for (int k = 0; k < 16; ++k) A2c[d][m][k] = (_Float16)w2[k];
        if (m < 3) {
            const float* w3 = W3 + (d * 3 + m) * 16;
#pragma unroll
            for (int k = 0; k < 16; ++k) A3c[d][m][k] = (_Float16)w3[k];
        } else {
#pragma unroll
            for (int k = 0; k < 16; ++k) A3c[d][m][k] = (_Float16)0.f;
        }
        B1c[d][m] = b1[d * 16 + m];
        B2c[d][m] = b2[d * 16 + m];
        B3c[d][m] = (m < 3) ? b3[d * 3 + m] : 0.f;
    }
    __syncthreads();

    const int lane = threadIdx.x & 63;
    const int wave = threadIdx.x >> 6;
    const int q = lane >> 4;        // quad 0..3
    const int n16 = lane & 15;      // column (point) within tile

    const int base = blockIdx.x * PTS_PER_BLOCK + wave * (TILES_PER_WAVE * 16);

    // ---- x B-frags: quad 0 holds k=0..3 = {x0,x1,x2,0}; quads 1..3 zero ----
    Frag xf[TILES_PER_WAVE];
#pragma unroll
    for (int t = 0; t < TILES_PER_WAVE; ++t) {
        const int pt = base + t * 16 + n16;
        float x0 = 0.f, x1 = 0.f, x2 = 0.f;
        if (q == 0 && pt < N) {
            x0 = x[pt];
            x1 = x[(size_t)N + pt];
            x2 = x[2 * (size_t)N + pt];
        }
        xf[t].i[0] = pkrtz(x0, x1);
        xf[t].i[1] = pkrtz(x2, 0.f);
    }

#pragma unroll 1
    for (int d = 0; d < 16; ++d) {
        // A-frags from LDS. a1: all quads read the same row (broadcast) —
        // harmless for q>=1 since xf's quads>=1 are zero.
        Frag a1, a2, a3;
        a1.v = *(const half4_t*)&A1c[d][n16][0];
        a2.v = *(const half4_t*)&A2c[d][n16][q * 4];
        a3.v = *(const half4_t*)&A3c[d][n16][q * 4];
        const float4_t bias1 = *(const float4_t*)&B1c[d][q * 4];
        const float4_t bias2 = *(const float4_t*)&B2c[d][q * 4];
        const float4_t bias3 = *(const float4_t*)&B3c[d][q * 4];

#pragma unroll
        for (int t = 0; t < TILES_PER_WAVE; ++t) {
            // Layer 1: h1 = relu(W1 x + b1)   (D-layout == next B-layout)
            float4_t acc = bias1;
            acc = MFMA16(a1.v, xf[t].v, acc);
            Frag bf;
            bf.i[0] = pkrtz(fmaxf(acc.x, 0.f), fmaxf(acc.y, 0.f));
            bf.i[1] = pkrtz(fmaxf(acc.z, 0.f), fmaxf(acc.w, 0.f));
            // Layer 2
            acc = bias2;
            acc = MFMA16(a2.v, bf.v, acc);
            Frag cf;
            cf.i[0] = pkrtz(fmaxf(acc.x, 0.f), fmaxf(acc.y, 0.f));
            cf.i[1] = pkrtz(fmaxf(acc.z, 0.f), fmaxf(acc.w, 0.f));
            // Layer 3 (no relu)
            acc = bias3;
            acc = MFMA16(a3.v, cf.v, acc);
            // quad 0 holds rows 0..3 -> outputs o=0,1,2 of point n16
            const int pt = base + t * 16 + n16;
            if (q == 0 && pt < N) {
                out[(size_t)(d * 3 + 0) * N + pt] = acc.x;
                out[(size_t)(d * 3 + 1) * N + pt] = acc.y;
                out[(size_t)(d * 3 + 2) * N + pt] = acc.z;
            }
        }
    }
}

extern "C" void kernel_launch(void* const* d_in, const int* in_sizes, int n_in,
                              void* d_out, int out_size, void* d_ws, size_t ws_size,
                              hipStream_t stream) {
    const float* x  = (const float*)d_in[0];
    const float* W1 = (const float*)d_in[1];
    const float* b1 = (const float*)d_in[2];
    const float* W2 = (const float*)d_in[3];
    const float* b2 = (const float*)d_in[4];
    const float* W3 = (const float*)d_in[5];
    const float* b3 = (const float*)d_in[6];
    float* out = (float*)d_out;

    const int N = in_sizes[0] / 3;  // x is [1,3,N]
    const int grid = (N + PTS_PER_BLOCK - 1) / PTS_PER_BLOCK;
    fields_mfma16_kernel<<<grid, 256, 0, stream>>>(x, W1, b1, W2, b2, W3, b3, out, N);
}